// Round 2
// baseline (1574.858 us; speedup 1.0000x reference)
//
#include <hip/hip_runtime.h>

#define BB 4
#define C 128
#define HH 128
#define WW 128
#define HW 16384
#define K 8
#define O 384

// ---------------- Kernel 1: qkv = w_qkv @ x, output transposed to (B,HW,C) ----
// Weight loads scalarized via readfirstlane -> s_load_dwordx4 (constant cache).
__global__ __launch_bounds__(256) void k_qkv(const float* __restrict__ x,
                                             const float* __restrict__ w_qkv,
                                             float* __restrict__ q_t,
                                             float* __restrict__ k_t,
                                             float* __restrict__ v_t) {
  __shared__ float Xs[C * 64];
  const int b = blockIdx.y;
  const int pix0 = blockIdx.x * 64;
  const int t = threadIdx.x;
  const float* xb = x + (size_t)b * C * HW + pix0;
  #pragma unroll
  for (int i = 0; i < 32; ++i) {
    int linear = i * 256 + t;
    int c = linear >> 6, p = linear & 63;
    Xs[c * 64 + p] = xb[(size_t)c * HW + p];   // coalesced read, conflict-free write
  }
  __syncthreads();
  const int wave = __builtin_amdgcn_readfirstlane(t >> 6);  // SGPR wave id
  const int lane = t & 63;
  const size_t outpix = (size_t)b * HW + pix0 + lane;
  for (int i = 0; i < 12; ++i) {
    const int o_base = (wave + 4 * i) * 8;     // scalar: 48 chunks of 8 outputs
    float acc[8] = {0, 0, 0, 0, 0, 0, 0, 0};
    const float* wr = w_qkv + (size_t)o_base * C;  // SGPR base pointer
    #pragma unroll
    for (int c = 0; c < C; c += 4) {
      float xv0 = Xs[(c + 0) * 64 + lane];
      float xv1 = Xs[(c + 1) * 64 + lane];
      float xv2 = Xs[(c + 2) * 64 + lane];
      float xv3 = Xs[(c + 3) * 64 + lane];
      #pragma unroll
      for (int j = 0; j < 8; ++j) {
        const float4 w4 = *(const float4*)(wr + j * C + c);  // s_load_dwordx4
        acc[j] += w4.x * xv0 + w4.y * xv1 + w4.z * xv2 + w4.w * xv3;
      }
    }
    float* dst;
    if (o_base < 128)      dst = q_t + outpix * C + o_base;
    else if (o_base < 256) dst = k_t + outpix * C + (o_base - 128);
    else                   dst = v_t + outpix * C + (o_base - 256);
    *(float4*)(dst)     = make_float4(acc[0], acc[1], acc[2], acc[3]);
    *(float4*)(dst + 4) = make_float4(acc[4], acc[5], acc[6], acc[7]);
  }
}

// ---------------- Kernel 2: fused bilinear gather + attention + softmax -------
__global__ __launch_bounds__(256) void k_attn(const float* __restrict__ q_t,
                                              const float* __restrict__ k_t,
                                              const float* __restrict__ v_t,
                                              const int* __restrict__ psf,
                                              const float* __restrict__ delta,
                                              float* __restrict__ ao) {
  const int t = threadIdx.x;
  const int wave = t >> 6, lane = t & 63;
  const int pix = blockIdx.x * 4 + wave;      // 0..65535
  const int b = pix >> 14;

  const float* qp = q_t + (size_t)pix * C + 2 * lane;
  const float qx = qp[0], qy = qp[1];

  float wgt[K][4];
  int dx0[K], dy0[K];
  #pragma unroll
  for (int k = 0; k < K; ++k) {
    float s0 = tanhf(delta[k * 2 + 0]) * 4.0f;  // col shift (grid[...,0] -> x)
    float s1 = tanhf(delta[k * 2 + 1]) * 4.0f;  // row shift
    float f0 = floorf(s0), f1 = floorf(s1);
    dx0[k] = (int)f0; dy0[k] = (int)f1;
    float fx = s0 - f0, fy = s1 - f1;
    wgt[k][0] = (1.0f - fx) * (1.0f - fy);
    wgt[k][1] = fx * (1.0f - fy);
    wgt[k][2] = (1.0f - fx) * fy;
    wgt[k][3] = fx * fy;
  }

  const int* pp = psf + (size_t)pix * K * 2;
  const float* kb = k_t + (size_t)b * HW * C;
  const float* vb = v_t + (size_t)b * HW * C;

  float logits[K];
  float2 vs[K];
  #pragma unroll
  for (int k = 0; k < K; ++k) {
    const int a0 = pp[k * 2 + 0];   // col anchor
    const int a1 = pp[k * 2 + 1];   // row anchor
    const int x0 = a0 + dx0[k], x1 = x0 + 1;
    const int y0 = a1 + dy0[k], y1 = y0 + 1;
    float ksx = 0, ksy = 0, vsx = 0, vsy = 0;
    #pragma unroll
    for (int cn = 0; cn < 4; ++cn) {
      const int xi = (cn & 1) ? x1 : x0;
      const int yi = (cn & 2) ? y1 : y0;
      const bool valid = (xi >= 0) & (xi <= WW - 1) & (yi >= 0) & (yi <= HH - 1);
      const float wv = valid ? wgt[k][cn] : 0.0f;
      const int xc = min(max(xi, 0), WW - 1);
      const int yc = min(max(yi, 0), HH - 1);
      const size_t idx = ((size_t)(yc * WW + xc)) * C + 2 * lane;
      const float2 kk = *(const float2*)(kb + idx);   // 512B/wave coalesced
      const float2 vv = *(const float2*)(vb + idx);
      ksx += wv * kk.x; ksy += wv * kk.y;
      vsx += wv * vv.x; vsy += wv * vv.y;
    }
    vs[k] = make_float2(vsx, vsy);
    float d = qx * ksx + qy * ksy;
    #pragma unroll
    for (int off = 32; off > 0; off >>= 1) d += __shfl_xor(d, off);
    logits[k] = d * 0.08838834764831845f;   // C^-0.5
  }

  float m = logits[0];
  #pragma unroll
  for (int k = 1; k < K; ++k) m = fmaxf(m, logits[k]);
  float e[K], den = 0.0f;
  #pragma unroll
  for (int k = 0; k < K; ++k) { e[k] = expf(logits[k] - m); den += e[k]; }
  const float inv = 1.0f / den;
  float ox = 0, oy = 0;
  #pragma unroll
  for (int k = 0; k < K; ++k) { float p = e[k] * inv; ox += p * vs[k].x; oy += p * vs[k].y; }
  *(float2*)(ao + (size_t)pix * C + 2 * lane) = make_float2(ox, oy);
}

// ---------------- Kernel 3: out = x + w_proj @ attn_out ----------------------
__global__ __launch_bounds__(256) void k_proj(const float* __restrict__ ao,
                                              const float* __restrict__ w_proj,
                                              const float* __restrict__ x,
                                              float* __restrict__ out) {
  __shared__ float As[C * 65];               // +1 pad: conflict-free transpose
  const int b = blockIdx.y;
  const int pix0 = blockIdx.x * 64;
  const int t = threadIdx.x;
  const float* ab = ao + ((size_t)b * HW + pix0) * C;
  #pragma unroll
  for (int i = 0; i < 32; ++i) {
    int linear = i * 256 + t;
    int c = linear & 127, p = linear >> 7;
    As[c * 65 + p] = ab[p * C + c];          // coalesced read, conflict-free write
  }
  __syncthreads();
  const int wave = __builtin_amdgcn_readfirstlane(t >> 6);  // SGPR wave id
  const int lane = t & 63;
  const size_t xoff = (size_t)b * C * HW + pix0 + lane;
  for (int i = 0; i < 4; ++i) {
    const int o_base = (wave * 4 + i) * 8;
    float acc[8] = {0, 0, 0, 0, 0, 0, 0, 0};
    const float* wr = w_proj + (size_t)o_base * C;  // SGPR base pointer
    #pragma unroll
    for (int c = 0; c < C; c += 4) {
      float a0 = As[(c + 0) * 65 + lane];
      float a1 = As[(c + 1) * 65 + lane];
      float a2 = As[(c + 2) * 65 + lane];
      float a3 = As[(c + 3) * 65 + lane];
      #pragma unroll
      for (int j = 0; j < 8; ++j) {
        const float4 w4 = *(const float4*)(wr + j * C + c);  // s_load_dwordx4
        acc[j] += w4.x * a0 + w4.y * a1 + w4.z * a2 + w4.w * a3;
      }
    }
    #pragma unroll
    for (int j = 0; j < 8; ++j) {
      const size_t gi = xoff + (size_t)(o_base + j) * HW;
      out[gi] = x[gi] + acc[j];              // coalesced
    }
  }
}

extern "C" void kernel_launch(void* const* d_in, const int* in_sizes, int n_in,
                              void* d_out, int out_size, void* d_ws, size_t ws_size,
                              hipStream_t stream) {
  const float* x      = (const float*)d_in[0];
  const int*   psf    = (const int*)d_in[1];
  const float* delta  = (const float*)d_in[2];
  const float* w_qkv  = (const float*)d_in[3];
  const float* w_proj = (const float*)d_in[4];
  float* out = (float*)d_out;

  const size_t N = (size_t)BB * HW * C;   // 8388608 floats = 32MB
  float* q_t = out;                        // reuse d_out as q scratch (exactly N)
  float* k_t = (float*)d_ws;
  float* v_t = k_t + N;
  float* ao  = v_t + N;                    // ws need: 96MB

  k_qkv<<<dim3(HW / 64, BB), 256, 0, stream>>>(x, w_qkv, q_t, k_t, v_t);
  k_attn<<<dim3(HW * BB / 4), 256, 0, stream>>>(q_t, k_t, v_t, psf, delta, ao);
  k_proj<<<dim3(HW / 64, BB), 256, 0, stream>>>(ao, w_proj, x, out);
}

// Round 3
// 233.617 us; speedup vs baseline: 6.7412x; 6.7412x over previous
//
#include <hip/hip_runtime.h>

#define HW 16384
#define C 128

typedef __attribute__((ext_vector_type(8))) short short8;
typedef __attribute__((ext_vector_type(4))) float f32x4;

__device__ __forceinline__ unsigned short f2bf(float f) {
  union { float f; unsigned u; } v; v.f = f;
  return (unsigned short)((v.u + 0x7fffu + ((v.u >> 16) & 1u)) >> 16);
}
__device__ __forceinline__ float bf2f(unsigned u16) {
  union { unsigned u; float f; } v; v.u = u16 << 16;
  return v.f;
}
__device__ __forceinline__ unsigned long long pk4(float a, float b, float c, float d) {
  return (unsigned long long)f2bf(a) | ((unsigned long long)f2bf(b) << 16) |
         ((unsigned long long)f2bf(c) << 32) | ((unsigned long long)f2bf(d) << 48);
}

// ---------------- Kernel 1: qkv = w_qkv @ x  (bf16 MFMA) ----------------------
// Block tile: 128 pixels (M) x 128 out-ch (N), K=128. Output bf16, pixel-major.
__global__ __launch_bounds__(256) void k_qkv(const float* __restrict__ x,
                                             const float* __restrict__ w_qkv,
                                             unsigned short* __restrict__ qb,
                                             unsigned short* __restrict__ kb,
                                             unsigned short* __restrict__ vb) {
  __shared__ __align__(16) unsigned short Xs[128 * 128];  // [pix][k] xor-swizzled
  __shared__ __align__(16) unsigned short Ws[128 * 128];  // [och][k] xor-swizzled
  const int t = threadIdx.x;
  const int gpix0 = blockIdx.x * 128;
  const int b = gpix0 >> 14;
  const int hw0 = gpix0 & (HW - 1);
  const int och0 = blockIdx.y * 128;

  // stage X (fp32 channel-major -> bf16 [pix][k]): 4 c-rows per iter
  const float* xb = x + (size_t)b * C * HW + hw0;
  #pragma unroll
  for (int i = 0; i < 16; ++i) {
    int linear = i * 256 + t;
    int p = linear & 127;
    int c4 = (linear >> 7) * 4;
    float a0 = xb[(size_t)(c4 + 0) * HW + p];
    float a1 = xb[(size_t)(c4 + 1) * HW + p];
    float a2 = xb[(size_t)(c4 + 2) * HW + p];
    float a3 = xb[(size_t)(c4 + 3) * HW + p];
    int cc = c4 ^ ((p & 7) << 3);
    *(unsigned long long*)&Xs[p * 128 + cc] = pk4(a0, a1, a2, a3);
  }
  // stage W (row-major [och][k], no transpose)
  const float* wb = w_qkv + (size_t)och0 * C;
  #pragma unroll
  for (int i = 0; i < 16; ++i) {
    int linear = i * 256 + t;
    int c4 = (linear & 31) * 4;
    int o = linear >> 5;
    float4 w4 = *(const float4*)(wb + (size_t)o * C + c4);
    int cc = c4 ^ ((o & 7) << 3);
    *(unsigned long long*)&Ws[o * 128 + cc] = pk4(w4.x, w4.y, w4.z, w4.w);
  }
  __syncthreads();

  const int wave = t >> 6, lane = t & 63;
  const int wr = wave >> 1, wc = wave & 1;   // wr: pixel half, wc: och half
  const int rsel = lane & 15, quad = lane >> 4;

  f32x4 acc[4][4];
  #pragma unroll
  for (int mi = 0; mi < 4; ++mi)
    #pragma unroll
    for (int ni = 0; ni < 4; ++ni) acc[mi][ni] = (f32x4){0.f, 0.f, 0.f, 0.f};

  #pragma unroll
  for (int ks = 0; ks < 4; ++ks) {
    const int koff = ks * 32 + quad * 8;
    short8 afr[4], bfr[4];
    #pragma unroll
    for (int mi = 0; mi < 4; ++mi) {
      int r = wr * 64 + mi * 16 + rsel;
      afr[mi] = *(const short8*)&Xs[r * 128 + (koff ^ ((r & 7) << 3))];
    }
    #pragma unroll
    for (int ni = 0; ni < 4; ++ni) {
      int r = wc * 64 + ni * 16 + rsel;
      bfr[ni] = *(const short8*)&Ws[r * 128 + (koff ^ ((r & 7) << 3))];
    }
    #pragma unroll
    for (int mi = 0; mi < 4; ++mi)
      #pragma unroll
      for (int ni = 0; ni < 4; ++ni)
        acc[mi][ni] = __builtin_amdgcn_mfma_f32_16x16x32_bf16(afr[mi], bfr[ni], acc[mi][ni], 0, 0, 0);
  }

  // epilogue: D col(lane&15)=och, row(quad*4+reg)=pixel -> store bf16 [pix][ch]
  unsigned short* dst = (och0 == 0) ? qb : ((och0 == 128) ? kb : vb);
  #pragma unroll
  for (int mi = 0; mi < 4; ++mi)
    #pragma unroll
    for (int ni = 0; ni < 4; ++ni)
      #pragma unroll
      for (int r = 0; r < 4; ++r) {
        int pix = gpix0 + wr * 64 + mi * 16 + quad * 4 + r;
        int ch = wc * 64 + ni * 16 + rsel;
        dst[(size_t)pix * C + ch] = f2bf(acc[mi][ni][r]);
      }
}

// ---------------- Kernel 2: fused bilinear gather + attention + softmax -------
// One wave per pixel; lane owns 2 channels (bf16x2). Batched butterfly reduce.
__global__ __launch_bounds__(256) void k_attn(const unsigned short* __restrict__ qb,
                                              const unsigned short* __restrict__ kb,
                                              const unsigned short* __restrict__ vb,
                                              const int* __restrict__ psf,
                                              const float* __restrict__ delta,
                                              unsigned short* __restrict__ ao) {
  const int t = threadIdx.x;
  const int wave = t >> 6, lane = t & 63;
  const int pix = blockIdx.x * 4 + wave;
  const int b = pix >> 14;

  const unsigned* q32 = (const unsigned*)qb;
  const unsigned* k32 = (const unsigned*)kb + (size_t)b * HW * 64;
  const unsigned* v32 = (const unsigned*)vb + (size_t)b * HW * 64;

  unsigned qp = q32[(size_t)pix * 64 + lane];
  const float qx = bf2f(qp & 0xffffu), qy = bf2f(qp >> 16);

  float wgt[8][4];
  int dx0[8], dy0[8];
  #pragma unroll
  for (int k = 0; k < 8; ++k) {
    float s0 = tanhf(delta[k * 2 + 0]) * 4.0f;  // col shift
    float s1 = tanhf(delta[k * 2 + 1]) * 4.0f;  // row shift
    float f0 = floorf(s0), f1 = floorf(s1);
    dx0[k] = (int)f0; dy0[k] = (int)f1;
    float fx = s0 - f0, fy = s1 - f1;
    wgt[k][0] = (1.0f - fx) * (1.0f - fy);
    wgt[k][1] = fx * (1.0f - fy);
    wgt[k][2] = (1.0f - fx) * fy;
    wgt[k][3] = fx * fy;
  }

  const int* pp = psf + (size_t)pix * 16;
  float dk[8];
  float2 vs[8];
  #pragma unroll
  for (int k = 0; k < 8; ++k) {
    const int x0 = pp[k * 2 + 0] + dx0[k], x1 = x0 + 1;
    const int y0 = pp[k * 2 + 1] + dy0[k], y1 = y0 + 1;
    float ksx = 0, ksy = 0, vsx = 0, vsy = 0;
    #pragma unroll
    for (int cn = 0; cn < 4; ++cn) {
      const int xi = (cn & 1) ? x1 : x0;
      const int yi = (cn & 2) ? y1 : y0;
      const bool valid = (xi >= 0) & (xi <= 127) & (yi >= 0) & (yi <= 127);
      const float wv = valid ? wgt[k][cn] : 0.0f;
      const int xc = min(max(xi, 0), 127);
      const int yc = min(max(yi, 0), 127);
      const size_t idx = (size_t)(yc * 128 + xc) * 64 + lane;
      const unsigned kk = k32[idx];
      const unsigned vv = v32[idx];
      ksx += wv * bf2f(kk & 0xffffu); ksy += wv * bf2f(kk >> 16);
      vsx += wv * bf2f(vv & 0xffffu); vsy += wv * bf2f(vv >> 16);
    }
    vs[k] = make_float2(vsx, vsy);
    dk[k] = qx * ksx + qy * ksy;
  }
  // batched 64-lane butterfly reduction of all 8 logits (ILP=8 per level)
  #pragma unroll
  for (int off = 32; off > 0; off >>= 1) {
    #pragma unroll
    for (int k = 0; k < 8; ++k) dk[k] += __shfl_xor(dk[k], off);
  }
  float m = dk[0] * 0.08838834764831845f;
  float lg[8];
  #pragma unroll
  for (int k = 0; k < 8; ++k) { lg[k] = dk[k] * 0.08838834764831845f; m = fmaxf(m, lg[k]); }
  float e[8], den = 0.0f;
  #pragma unroll
  for (int k = 0; k < 8; ++k) { e[k] = __expf(lg[k] - m); den += e[k]; }
  const float inv = 1.0f / den;
  float ox = 0, oy = 0;
  #pragma unroll
  for (int k = 0; k < 8; ++k) { float p = e[k] * inv; ox += p * vs[k].x; oy += p * vs[k].y; }
  ((unsigned*)ao)[(size_t)pix * 64 + lane] = (unsigned)f2bf(ox) | ((unsigned)f2bf(oy) << 16);
}

// ---------------- Kernel 3: out = x + w_proj @ ao  (bf16 MFMA) ----------------
// A=W (och=M), B=ao (pix=N): D col=pixel -> coalesced channel-major fp32 stores.
__global__ __launch_bounds__(256) void k_proj(const unsigned short* __restrict__ ao,
                                              const float* __restrict__ w_proj,
                                              const float* __restrict__ x,
                                              float* __restrict__ out) {
  __shared__ __align__(16) unsigned short As[128 * 128];  // [pix][k]
  __shared__ __align__(16) unsigned short Ws[128 * 128];  // [och][k]
  const int t = threadIdx.x;
  const int gpix0 = blockIdx.x * 128;
  const int b = gpix0 >> 14;
  const int hw0 = gpix0 & (HW - 1);

  #pragma unroll
  for (int i = 0; i < 8; ++i) {
    int linear = i * 256 + t;
    int c8 = (linear & 15) * 8;
    int p = linear >> 4;
    uint4 v = *(const uint4*)(ao + (size_t)(gpix0 + p) * C + c8);
    *(uint4*)&As[p * 128 + (c8 ^ ((p & 7) << 3))] = v;
  }
  #pragma unroll
  for (int i = 0; i < 16; ++i) {
    int linear = i * 256 + t;
    int c4 = (linear & 31) * 4;
    int o = linear >> 5;
    float4 w4 = *(const float4*)(w_proj + (size_t)o * C + c4);
    *(unsigned long long*)&Ws[o * 128 + (c4 ^ ((o & 7) << 3))] = pk4(w4.x, w4.y, w4.z, w4.w);
  }
  __syncthreads();

  const int wave = t >> 6, lane = t & 63;
  const int wr = wave >> 1, wc = wave & 1;   // wr: och half, wc: pixel half
  const int rsel = lane & 15, quad = lane >> 4;

  f32x4 acc[4][4];
  #pragma unroll
  for (int mi = 0; mi < 4; ++mi)
    #pragma unroll
    for (int ni = 0; ni < 4; ++ni) acc[mi][ni] = (f32x4){0.f, 0.f, 0.f, 0.f};

  #pragma unroll
  for (int ks = 0; ks < 4; ++ks) {
    const int koff = ks * 32 + quad * 8;
    short8 afr[4], bfr[4];
    #pragma unroll
    for (int mi = 0; mi < 4; ++mi) {
      int r = wr * 64 + mi * 16 + rsel;
      afr[mi] = *(const short8*)&Ws[r * 128 + (koff ^ ((r & 7) << 3))];
    }
    #pragma unroll
    for (int ni = 0; ni < 4; ++ni) {
      int r = wc * 64 + ni * 16 + rsel;
      bfr[ni] = *(const short8*)&As[r * 128 + (koff ^ ((r & 7) << 3))];
    }
    #pragma unroll
    for (int mi = 0; mi < 4; ++mi)
      #pragma unroll
      for (int ni = 0; ni < 4; ++ni)
        acc[mi][ni] = __builtin_amdgcn_mfma_f32_16x16x32_bf16(afr[mi], bfr[ni], acc[mi][ni], 0, 0, 0);
  }

  // epilogue: och = quad*4+reg (row), pixel = lane&15 (col); out = x + proj
  #pragma unroll
  for (int mi = 0; mi < 4; ++mi)
    #pragma unroll
    for (int ni = 0; ni < 4; ++ni)
      #pragma unroll
      for (int r = 0; r < 4; ++r) {
        int och = wr * 64 + mi * 16 + quad * 4 + r;
        int pixl = wc * 64 + ni * 16 + rsel;
        size_t addr = ((size_t)b * C + och) * HW + hw0 + pixl;
        out[addr] = x[addr] + acc[mi][ni][r];
      }
}

extern "C" void kernel_launch(void* const* d_in, const int* in_sizes, int n_in,
                              void* d_out, int out_size, void* d_ws, size_t ws_size,
                              hipStream_t stream) {
  const float* x      = (const float*)d_in[0];
  const int*   psf    = (const int*)d_in[1];
  const float* delta  = (const float*)d_in[2];
  const float* w_qkv  = (const float*)d_in[3];
  const float* w_proj = (const float*)d_in[4];
  float* out = (float*)d_out;

  const size_t N = (size_t)4 * HW * C;     // 8388608 elems
  unsigned short* qb = (unsigned short*)d_ws;       // 16 MB each
  unsigned short* kb = qb + N;
  unsigned short* vb = kb + N;
  unsigned short* ao = vb + N;                      // total 64 MB

  k_qkv<<<dim3(512, 3), 256, 0, stream>>>(x, w_qkv, qb, kb, vb);
  k_attn<<<dim3(HW), 256, 0, stream>>>(qb, kb, vb, psf, delta, ao);
  k_proj<<<dim3(512), 256, 0, stream>>>(ao, w_proj, x, out);
}